// Round 9
// baseline (234.538 us; speedup 1.0000x reference)
//
#include <hip/hip_runtime.h>

// RenderingModel: scatter-add of 64x64 filters at N particle positions onto a
// 512x512 canvas (cropped).
//
// R8 post-mortem: MLP 8->16 loads in flight was exactly neutral -> the 32x32
// gather is at a random-64B-line L2 throughput wall (~187 MB of split lines:
// windows start at random even offsets -> 1.9 lines/row-read, plus 95^2/64^2
// pad over-read). R9 restructure: FULL-WIDTH STRIPS.
//   Block = 2 canvas rows x 512 cols (x particle segment, grid.y=4).
//   Per hit: filter rows iA, iA+1 are needed IN FULL (all 64 cols) -> one
//   256B perfectly-coalesced wave-load (lane L reads dword 4L: lanes 0-31 =
//   row iA, lanes 32-63 = row iA+1). No pad reads, no line splits: total
//   gather = 8192 x ~65 rows x 128B ~= 68 MB contiguous (the unique-bytes
//   floor). The column shift moves into LDS addressing: 2x512 fp32 strip
//   accumulator updated with atomicAdd-on-shared (ds_add_f32, consecutive
//   addresses -> conflict-free). Bank = unpadded bf16 [256][64][64] = 2 MB
//   (half of one XCD L2). Epilogue: 1M coalesced global fp32 atomics.

#define H_  512
#define W_  512
#define FH_ 64
#define FW_ 64
#define NPARTS_ 256
#define STRIP_ 2
#define THREADS_ 256
#define SEG_LEN_ 2048
#define LIST_MAX_ 1024   // cnt mean ~260 (Poisson), 1024 is >40 sigma

__device__ __forceinline__ unsigned short f2bf(float f) {
    unsigned u = __float_as_uint(f);
    return (unsigned short)((u + 0x7fffu + ((u >> 16) & 1u)) >> 16);  // RNE
}

// Bank lives at d_ws + 128 B; the 128 B guard below it makes the iA = -1
// underflow read (gated off by the row-valid predicate) stay inside d_ws.
__global__ __launch_bounds__(256)
void pack_filters_kernel(const float* __restrict__ filters,
                         unsigned int* __restrict__ bank,  // bf16 pairs
                         float* __restrict__ out) {
    const int part = blockIdx.x;
    const int t    = threadIdx.x;
    const float*  src = filters + part * (FH_ * FW_);
    unsigned int* dst = bank + part * (FH_ * FW_ / 2);    // 2048 uints/part
#pragma unroll
    for (int it = 0; it < 8; ++it) {
        const int u = t + 256 * it;                       // uint slot [0,2048)
        dst[u] = (unsigned)f2bf(src[2 * u]) | ((unsigned)f2bf(src[2 * u + 1]) << 16);
    }
    // zero d_out (atomic epilogue needs zeros; harness poisons 0xAA)
    ((float4*)out)[part * 256 + t] = make_float4(0.f, 0.f, 0.f, 0.f);
}

__global__ __launch_bounds__(THREADS_, 4)
void render_strip_kernel(const int* __restrict__ phw,
                         const char* __restrict__ wsb,    // d_ws; bank at +128
                         float* __restrict__ out, int n) {
    __shared__ float s_acc[STRIP_ * W_];       // 4 KB strip accumulator
    __shared__ unsigned int s_list[LIST_MAX_];
    __shared__ int s_cnt;

    const int t  = threadIdx.x;
    const int r0 = blockIdx.x * STRIP_;        // first canvas row of strip
    const int k0 = blockIdx.y * SEG_LEN_;
    const int k1 = (k0 + SEG_LEN_ < n) ? (k0 + SEG_LEN_) : n;

    for (int i = t; i < STRIP_ * W_; i += THREADS_) s_acc[i] = 0.f;
    if (t == 0) s_cnt = 0;
    __syncthreads();

    // ---- Phase 1: row-range test + compaction (cols always hit: full width)
    // Strip rows y in [r0, r0+1] covered iff row in [r0-31, r0+33].
    for (int k = k0 + t; k < k1; k += THREADS_) {
        const int part = phw[k * 3 + 0];
        const int row  = phw[k * 3 + 1];
        const int col  = phw[k * 3 + 2];
        if (row >= r0 - (FH_ / 2 - 1) && row <= r0 + STRIP_ - 1 + FH_ / 2) {
            const int idx = atomicAdd(&s_cnt, 1);
            if (idx < LIST_MAX_)   // statistically unreachable guard
                s_list[idx] = ((unsigned)part << 18) | ((unsigned)row << 9) | (unsigned)col;
        }
    }
    __syncthreads();
    const int cnt = (s_cnt < LIST_MAX_) ? s_cnt : LIST_MAX_;

    // ---- Phase 2: wave w handles hits w, w+4, ... ----
    // Lane L: rsel = L>>5 (strip row), filter cols jc, jc+1 where jc=(L&31)*2.
    const int w    = t >> 6;
    const int lane = t & 63;
    const int rsel = lane >> 5;
    const int jc   = (lane & 31) * 2;
    float* accrow  = s_acc + rsel * W_;
    const int lane4 = lane * 4;

    auto proc = [&](unsigned v) {
        const int col  = (int)(v & 511u);
        const int row  = (int)((v >> 9) & 511u);
        const int part = (int)(v >> 18);
        const int iA   = r0 - row + (FH_ / 2);            // in [-1, 63]
        // one coalesced 256B wave-load: rows iA (lanes 0-31), iA+1 (32-63)
        const int off  = part * (FH_ * FW_ * 2) + iA * (FW_ * 2) + lane4;
        const unsigned u = *(const unsigned*)(wsb + 128 + off);
        const int i = iA + rsel;                          // this lane's row
        if ((unsigned)i < (unsigned)FH_) {                // near-uniform branch
            const float f0 = __uint_as_float(u << 16);    // bf16 -> f32
            const float f1 = __uint_as_float(u & 0xffff0000u);
            const int cc = col - (FW_ / 2) + jc;          // canvas col
            if ((unsigned)cc       < (unsigned)W_) atomicAdd(&accrow[cc], f0);
            if ((unsigned)(cc + 1) < (unsigned)W_) atomicAdd(&accrow[cc + 1], f1);
        }
    };

    int k = w;
    for (; k + 12 < cnt; k += 16) {       // 4 hits per round, loads hoistable
        const unsigned a = s_list[k];
        const unsigned b = s_list[k + 4];
        const unsigned c = s_list[k + 8];
        const unsigned d = s_list[k + 12];
        proc(a); proc(b); proc(c); proc(d);
    }
    for (; k < cnt; k += 4) proc(s_list[k]);

    // ---- Epilogue: strip accumulator -> global (coalesced atomics) ----
    __syncthreads();
    for (int i = t; i < STRIP_ * W_; i += THREADS_) {
        atomicAdd(&out[(r0 + (i >> 9)) * W_ + (i & (W_ - 1))], s_acc[i]);
    }
}

extern "C" void kernel_launch(void* const* d_in, const int* in_sizes, int n_in,
                              void* d_out, int out_size, void* d_ws, size_t ws_size,
                              hipStream_t stream) {
    const int*   phw     = (const int*)d_in[0];
    const float* filters = (const float*)d_in[1];
    float*       out     = (float*)d_out;
    unsigned int* bank   = (unsigned int*)((char*)d_ws + 128);  // 2 MB bank
    const int n = in_sizes[0] / 3;

    pack_filters_kernel<<<NPARTS_, 256, 0, stream>>>(filters, bank, out);

    const int segs = (n + SEG_LEN_ - 1) / SEG_LEN_;   // = 4 at N=8192
    dim3 grid(H_ / STRIP_, segs);
    render_strip_kernel<<<grid, THREADS_, 0, stream>>>(
        phw, (const char*)d_ws, out, n);
}